// Round 8
// baseline (1075.346 us; speedup 1.0000x reference)
//
#include <hip/hip_runtime.h>
#include <hip/hip_bf16.h>
#include <math.h>

// Problem constants (from reference)
#define S_   3
#define B_   32
#define C_   512
#define E_   256      // INPUT_DIM
#define H_   512      // HIDDEN_DIM
#define P_   256      // PRED_LEN
#define T_   49152    // S*B*C tokens (expert weights shared across scales -> flatten)
#define TBC_ 16384    // B*C

typedef __attribute__((ext_vector_type(8))) short v_s16x8;  // 8 bf16 (4 VGPR)
typedef __attribute__((ext_vector_type(4))) float v_f32x4;  // MFMA accumulator

__device__ __forceinline__ float gelu_f(float x) {
  // exact gelu (approximate=False): 0.5*x*(1+erf(x/sqrt(2)))
  return 0.5f * x * (1.0f + erff(x * 0.70710678118654752440f));
}

__device__ __forceinline__ void gload_lds16(const void* g, void* l) {
  // async global->LDS, 16B per lane; LDS dest = wave-uniform base + lane*16
  __builtin_amdgcn_global_load_lds((const __attribute__((address_space(1))) void*)g,
                                   (__attribute__((address_space(3))) void*)l, 16, 0, 0);
}

// ---------------------------------------------------------------------------
// bf16 MFMA GEMM, m97 structure: 128x128 tile, BK=32, 4 waves (2x2 of 64x64),
// 16x16x32 MFMA, global_load_lds width 16, 2 barriers per K-step.
// A [M,K] bf16 (row stride lda elems), Bt [N,K] bf16 (row stride ldb elems).
// SPLITA: A has 256 real cols; virtual K=768 = [A_hi | A_lo | A_hi]
//         (split-bf16 fp32-emulation: acc = hi*hi + lo*hi + hi*lo).
// MODE 0: bf16 gelu(acc+bias)
// MODE 2: f32 acc+bias
// MODE 4: bf16 wtok[row][eidxBase+(col>>9)]*gelu(acc+bias)  [scaled hidden]
// MODE 6: f32 pred: STORE -> acc + sum_e wtok[row][e]*Ball[e*256+col]; else +=
// MODE 8: router+logits fusion: h=gelu(acc+bias); atomicAdd partial h@w2
//         into Cout=wtok[T][8] (Ball param carries w2 [512][8]). No h stored.
// ---------------------------------------------------------------------------
template<int MODE, bool STORE, bool SPLITA>
__global__ __launch_bounds__(256)
void gemm_bf16_k(const __hip_bfloat16* __restrict__ A,
                 const __hip_bfloat16* __restrict__ Bt,
                 const float* __restrict__ bias,
                 void* __restrict__ Cout,
                 const float* __restrict__ wtok,
                 int M, int N, int K, int eidxBase,
                 const __hip_bfloat16* __restrict__ Alo,
                 int lda, int ldb, int ldc,
                 const float* __restrict__ Ball)
{
  __shared__ __align__(16) unsigned short As[4096];  // [128][32] bf16
  __shared__ __align__(16) unsigned short Bs[4096];  // [128][32] bf16 (rows = out cols)
  __shared__ float XtraS[(MODE == 8) ? 4608 : ((MODE == 6 && STORE) ? 2048 : 1)];
  const int tid  = threadIdx.x;
  const int wid  = tid >> 6;
  const int lane = tid & 63;
  const int wm = wid >> 1, wn = wid & 1;
  const int l15 = lane & 15, l4 = lane >> 4;

  if constexpr (MODE == 8) {
    for (int i = tid; i < 4096; i += 256) XtraS[i] = Ball[i];      // rw2 [512][8]
    for (int i = tid; i < 512; i += 256) XtraS[4096 + i] = bias[i]; // rb1
    // visible after first in-loop __syncthreads(), consumed only in epilogue
  } else if constexpr (MODE == 6 && STORE) {
    for (int i = tid; i < 2048; i += 256) XtraS[i] = Ball[i];      // 8 expert biases
  }

  v_f32x4 acc[4][4] = {};

  const size_t ArsB = (size_t)lda * 2;   // A row stride bytes
  const size_t BrsB = (size_t)ldb * 2;   // Bt row stride bytes
  const char* AgHi = (const char*)A + (size_t)blockIdx.x * 128 * ArsB;
  const char* AgLo = SPLITA ? ((const char*)Alo + (size_t)blockIdx.x * 128 * ArsB) : nullptr;
  const char* Bg   = (const char*)Bt + (size_t)blockIdx.y * 128 * BrsB;

  // staging geometry: 8KB per tile = 4 waves x 2 chunks x 64 lanes x 16B
  const int ob0 = (0 * 4 + wid) * 1024 + lane * 16;
  const int ob1 = (1 * 4 + wid) * 1024 + lane * 16;
  const int r0 = ob0 >> 6, kb0 = ob0 & 63;
  const int r1 = ob1 >> 6, kb1 = ob1 & 63;
  char* lA0 = (char*)As + (0 * 4 + wid) * 1024;
  char* lA1 = (char*)As + (1 * 4 + wid) * 1024;
  char* lB0 = (char*)Bs + (0 * 4 + wid) * 1024;
  char* lB1 = (char*)Bs + (1 * 4 + wid) * 1024;
  const size_t aoff0 = (size_t)r0 * ArsB + kb0;
  const size_t aoff1 = (size_t)r1 * ArsB + kb1;
  const char* gB0 = Bg + (size_t)r0 * BrsB + kb0;
  const char* gB1 = Bg + (size_t)r1 * BrsB + kb1;

  for (int kt = 0; kt < K; kt += 32) {
    const char* Asrc = AgHi;
    size_t akt = (size_t)kt * 2;
    if (SPLITA) {
      akt = (size_t)(kt & 255) * 2;
      if ((kt >> 8) == 1) Asrc = AgLo;
    }
    size_t bkt = (size_t)kt * 2;
    gload_lds16(Asrc + aoff0 + akt, lA0);
    gload_lds16(Asrc + aoff1 + akt, lA1);
    gload_lds16(gB0 + bkt, lB0);
    gload_lds16(gB1 + bkt, lB1);
    __syncthreads();   // vmcnt drain + barrier
    v_s16x8 af[4], bfv[4];
#pragma unroll
    for (int m = 0; m < 4; ++m)
      af[m] = *(const v_s16x8*)(As + (wm * 64 + m * 16 + l15) * 32 + l4 * 8);
#pragma unroll
    for (int n = 0; n < 4; ++n)
      bfv[n] = *(const v_s16x8*)(Bs + (wn * 64 + n * 16 + l15) * 32 + l4 * 8);
#pragma unroll
    for (int m = 0; m < 4; ++m)
#pragma unroll
      for (int n = 0; n < 4; ++n)
        acc[m][n] = __builtin_amdgcn_mfma_f32_16x16x32_bf16(af[m], bfv[n], acc[m][n], 0, 0, 0);
    __syncthreads();   // protect LDS before next stage
  }

  const int crow0 = blockIdx.x * 128 + wm * 64;
  const int ccol0 = blockIdx.y * 128 + wn * 64;

  if constexpr (MODE == 8) {
    // fused router logits: partial (gelu(h)) @ w2 -> atomicAdd into wtok
    float* Lg = (float*)Cout;
#pragma unroll
    for (int m = 0; m < 4; ++m) {
#pragma unroll
      for (int j = 0; j < 4; ++j) {
        float pe[8];
#pragma unroll
        for (int e = 0; e < 8; ++e) pe[e] = 0.f;
#pragma unroll
        for (int n = 0; n < 4; ++n) {
          const int col = ccol0 + n * 16 + l15;
          const float h = gelu_f(acc[m][n][j] + XtraS[4096 + col]);
          const float* w2r = &XtraS[col * 8];
#pragma unroll
          for (int e = 0; e < 8; ++e) pe[e] += h * w2r[e];
        }
#pragma unroll
        for (int off = 1; off < 16; off <<= 1)
#pragma unroll
          for (int e = 0; e < 8; ++e) pe[e] += __shfl_xor(pe[e], off);
        if (l15 == 0) {
          const int row = crow0 + m * 16 + l4 * 4 + j;
#pragma unroll
          for (int e = 0; e < 8; ++e) atomicAdd(&Lg[(size_t)row * 8 + e], pe[e]);
        }
      }
    }
    return;
  }

  if constexpr (MODE == 6) {
    // fused final accumulate: pred[row*ldc+col]
    float* P = (float*)Cout;
#pragma unroll
    for (int m = 0; m < 4; ++m) {
      float4 w0[4], w1[4];
      if (STORE) {
#pragma unroll
        for (int j = 0; j < 4; ++j) {
          const float4* wp = (const float4*)&wtok[(size_t)(crow0 + m * 16 + l4 * 4 + j) * 8];
          w0[j] = wp[0]; w1[j] = wp[1];
        }
      }
#pragma unroll
      for (int n = 0; n < 4; ++n) {
        const int col = ccol0 + n * 16 + l15;
        float bs[8];
        if (STORE) {
#pragma unroll
          for (int e = 0; e < 8; ++e) bs[e] = XtraS[e * 256 + col];
        }
#pragma unroll
        for (int j = 0; j < 4; ++j) {
          const int row = crow0 + m * 16 + l4 * 4 + j;
          float v = acc[m][n][j];
          if (STORE) {
            v += bs[0] * w0[j].x + bs[1] * w0[j].y + bs[2] * w0[j].z + bs[3] * w0[j].w
               + bs[4] * w1[j].x + bs[5] * w1[j].y + bs[6] * w1[j].z + bs[7] * w1[j].w;
            P[(size_t)row * ldc + col] = v;
          } else {
            P[(size_t)row * ldc + col] += v;
          }
        }
      }
    }
    return;
  }

#pragma unroll
  for (int m = 0; m < 4; ++m) {
    float wv[4];
    if (MODE == 4) {
      const int e4 = eidxBase + (ccol0 >> 9);
#pragma unroll
      for (int j = 0; j < 4; ++j)
        wv[j] = wtok[(size_t)(crow0 + m * 16 + l4 * 4 + j) * 8 + e4];
    }
#pragma unroll
    for (int n = 0; n < 4; ++n) {
      const int col = ccol0 + n * 16 + l15;
      const float bv = bias[col];
#pragma unroll
      for (int j = 0; j < 4; ++j) {
        const int row = crow0 + m * 16 + l4 * 4 + j;
        float v = acc[m][n][j] + bv;
        if constexpr (MODE == 0) {
          ((__hip_bfloat16*)Cout)[(size_t)row * ldc + col] = __float2bfloat16(gelu_f(v));
        } else if constexpr (MODE == 2) {
          ((float*)Cout)[(size_t)row * ldc + col] = v;
        } else if constexpr (MODE == 4) {
          ((__hip_bfloat16*)Cout)[(size_t)row * ldc + col] = __float2bfloat16(wv[j] * gelu_f(v));
        }
      }
    }
  }
}

// ---------------------------------------------------------------------------
// logits finish: wtok holds raw logit sums (h@w2); add b2, softmax, entropy,
// top-2 masking -- all in place (each thread owns its row).
// ---------------------------------------------------------------------------
__global__ __launch_bounds__(256) void logits_finish_kernel(
    float* __restrict__ wtok, const float* __restrict__ b2, float* __restrict__ entp) {
  const int t = blockIdx.x * 256 + threadIdx.x;
  float* wp = wtok + (size_t)t * 8;
  float lg[8], we[8];
#pragma unroll
  for (int e = 0; e < 8; ++e) lg[e] = wp[e] + b2[e];
  float mx = lg[0];
#pragma unroll
  for (int e = 1; e < 8; ++e) mx = fmaxf(mx, lg[e]);
  float ssum = 0.f;
#pragma unroll
  for (int e = 0; e < 8; ++e) { we[e] = expf(lg[e] - mx); ssum += we[e]; }
#pragma unroll
  for (int e = 0; e < 8; ++e) we[e] = we[e] / ssum;
  float ent = 0.f;
#pragma unroll
  for (int e = 0; e < 8; ++e) ent += we[e] * logf(we[e] + 1e-8f);
  // top-2 of locals (ties -> lower index, matching lax.top_k)
  int i1 = 0; float v1 = we[2];
#pragma unroll
  for (int n = 1; n < 6; ++n) if (we[2 + n] > v1) { v1 = we[2 + n]; i1 = n; }
  int i2 = -1; float v2 = -1e30f;
#pragma unroll
  for (int n = 0; n < 6; ++n) if (n != i1 && we[2 + n] > v2) { v2 = we[2 + n]; i2 = n; }
  float ow[8];
  ow[0] = we[0]; ow[1] = we[1];
#pragma unroll
  for (int n = 0; n < 6; ++n) ow[2 + n] = 0.f;
  ow[2 + i1] = v1; ow[2 + i2] = v2;
#pragma unroll
  for (int e = 0; e < 8; ++e) wp[e] = ow[e];
  __shared__ float red[256];
  red[threadIdx.x] = ent;
  __syncthreads();
  for (int s = 128; s > 0; s >>= 1) {
    if (threadIdx.x < s) red[threadIdx.x] += red[threadIdx.x + s];
    __syncthreads();
  }
  if (threadIdx.x == 0) atomicAdd(entp, red[0]);
}

// ---------------------------------------------------------------------------
// small helper kernels
// ---------------------------------------------------------------------------
// zero wtok (393216 floats = 98304 float4, grid exactly 384x256) + entp
__global__ void zero_wtok_kernel(float4* __restrict__ w, float* __restrict__ entp) {
  const int i = blockIdx.x * 256 + threadIdx.x;
  w[i] = make_float4(0.f, 0.f, 0.f, 0.f);
  if (i == 0) entp[0] = 0.f;
}

__global__ void convert_x_kernel(const float* __restrict__ x,
                                 __hip_bfloat16* __restrict__ xb,
                                 __hip_bfloat16* __restrict__ xlo, int n4) {
  int stride = gridDim.x * blockDim.x;
  for (int i = blockIdx.x * blockDim.x + threadIdx.x; i < n4; i += stride) {
    float4 v = ((const float4*)x)[i];
    float vv[4] = {v.x, v.y, v.z, v.w};
    union { __hip_bfloat16 h[4]; ushort4 u; } hi, lo;
#pragma unroll
    for (int j = 0; j < 4; ++j) {
      hi.h[j] = __float2bfloat16(vv[j]);
      lo.h[j] = __float2bfloat16(vv[j] - __bfloat162float(hi.h[j]));
    }
    ((ushort4*)xb)[i] = hi.u;
    ((ushort4*)xlo)[i] = lo.u;
  }
}

// router W1 -> [N=512][K=768] bf16: cols 0..255 = W_hi, 256..511 = W_hi, 512..767 = W_lo
__global__ void build_router_w_kernel(const float* __restrict__ rw1,
                                      __hip_bfloat16* __restrict__ dst) {
  int i = blockIdx.x * 256 + threadIdx.x;   // 512*768 total
  int n = i / 768, k = i - n * 768;
  float src = rw1[(size_t)(k & 255) * 512 + n];
  __hip_bfloat16 hv = __float2bfloat16(src);
  dst[i] = (k < 512) ? hv : __float2bfloat16(src - __bfloat162float(hv));
}

// Ball[8][256] = [gb3_0;gb3_1;lb2_0..5]  (2048 floats, grid 8x256)
__global__ void build_ball_kernel(const float* __restrict__ gb3, const float* __restrict__ lb2,
                                  float* __restrict__ Ball) {
  int i = blockIdx.x * 256 + threadIdx.x;
  Ball[i] = (i < 512) ? gb3[i] : lb2[i - 512];
}

struct ConvDesc { const float* src; __hip_bfloat16* dst; int K; int N; int ldb; int koff; };
struct ConvArgs { ConvDesc d[20]; };

// dst[n*ldb + koff + k] = bf16(src[k*N+n]) : weight transpose+convert
__global__ void convert_wt_kernel(ConvArgs a) {
  ConvDesc c = a.d[blockIdx.y];
  int total = c.K * c.N;
  int stride = gridDim.x * blockDim.x;
  for (int e = blockIdx.x * blockDim.x + threadIdx.x; e < total; e += stride) {
    int n = e / c.K;
    int k = e - n * c.K;
    c.dst[(size_t)n * c.ldb + c.koff + k] = __float2bfloat16(c.src[(size_t)k * c.N + n]);
  }
}

// meanz[r][o] = mean_c pred[r*512+c][o], r = s*32+b
__global__ void mean_kernel(const float* __restrict__ pred, float* __restrict__ meanz) {
  int r = blockIdx.x, o = threadIdx.x;
  const float* p = pred + (size_t)r * 512 * 256 + o;
  float s0 = 0.f, s1 = 0.f, s2 = 0.f, s3 = 0.f;
  for (int c = 0; c < 512; c += 4) {
    s0 += p[(size_t)(c + 0) * 256]; s1 += p[(size_t)(c + 1) * 256];
    s2 += p[(size_t)(c + 2) * 256]; s3 += p[(size_t)(c + 3) * 256];
  }
  meanz[r * 256 + o] = (s0 + s1 + s2 + s3) * (1.0f / 512.0f);
}

__global__ void te_kernel(const float* __restrict__ meanz, const float* __restrict__ tw,
                          const float* __restrict__ tb, float* __restrict__ reprs) {
  __shared__ float row[256];
  int r = blockIdx.x, j = threadIdx.x;
  row[j] = meanz[r * 256 + j];
  __syncthreads();
  float a = 0.f;
  for (int k = 0; k < 256; ++k) a += row[k] * tw[k * 256 + j];
  reprs[r * 256 + j] = gelu_f(a + tb[j]);
}

__global__ void wc_kernel(const float* __restrict__ reprs, const float* __restrict__ wmem,
                          const float* __restrict__ wcw, const float* __restrict__ wcb,
                          float* __restrict__ sw) {
  __shared__ float red[128][3];
  int b = blockIdx.x, tid = threadIdx.x;
  float a0 = 0.f, a1 = 0.f, a2 = 0.f;
  for (int i = tid; i < 771; i += 128) {
    float cv = (i < 768) ? reprs[(i >> 8) * 8192 + b * 256 + (i & 255)] : wmem[i - 768];
    a0 += cv * wcw[i * 3 + 0]; a1 += cv * wcw[i * 3 + 1]; a2 += cv * wcw[i * 3 + 2];
  }
  red[tid][0] = a0; red[tid][1] = a1; red[tid][2] = a2;
  __syncthreads();
  for (int s = 64; s > 0; s >>= 1) {
    if (tid < s) {
      red[tid][0] += red[tid + s][0];
      red[tid][1] += red[tid + s][1];
      red[tid][2] += red[tid + s][2];
    }
    __syncthreads();
  }
  if (tid == 0) {
    float r[3]; float mx = -1e30f;
    for (int j = 0; j < 3; ++j) {
      float v = tanhf(red[0][j] + wcb[j]);
      r[j] = log1pf(expf(v));
      mx = fmaxf(mx, r[j]);
    }
    float s = 0.f;
    for (int j = 0; j < 3; ++j) { r[j] = expf(r[j] - mx); s += r[j]; }
    for (int j = 0; j < 3; ++j) sw[b * 3 + j] = r[j] / s;
  }
}

__global__ void weighted_kernel(const float* __restrict__ pred, const float* __restrict__ sw,
                                __hip_bfloat16* __restrict__ wb) {
  int t = blockIdx.x, o = threadIdx.x;
  int b = t >> 9;
  float s0 = sw[b * 3 + 0], s1 = sw[b * 3 + 1], s2 = sw[b * 3 + 2];
  size_t i = (size_t)t * 256 + o;
  float v = pred[i] * s0 + pred[i + (size_t)TBC_ * 256] * s1 + pred[i + (size_t)2 * TBC_ * 256] * s2;
  wb[i] = __float2bfloat16(v);
}

__global__ void finalize_kernel(const float* __restrict__ entp, float* __restrict__ out) {
  out[4194304] = -0.1f * entp[0] / 49152.0f;   // balance_loss = 0.1 * entropy
}

// ---------------------------------------------------------------------------
extern "C" void kernel_launch(void* const* d_in, const int* in_sizes, int n_in,
                              void* d_out, int out_size, void* d_ws, size_t ws_size,
                              hipStream_t stream) {
  const float* x    = (const float*)d_in[0];
  const float* rw1  = (const float*)d_in[1];
  const float* rb1  = (const float*)d_in[2];
  const float* rw2  = (const float*)d_in[3];
  const float* rb2  = (const float*)d_in[4];
  const float* gW1  = (const float*)d_in[5];
  const float* gb1  = (const float*)d_in[6];
  const float* gW2  = (const float*)d_in[7];
  const float* gb2  = (const float*)d_in[8];
  const float* gW3  = (const float*)d_in[9];
  const float* gb3  = (const float*)d_in[10];
  const float* lW1  = (const float*)d_in[11];
  const float* lb1  = (const float*)d_in[12];
  const float* lW2  = (const float*)d_in[13];
  const float* lb2  = (const float*)d_in[14];
  const float* tew  = (const float*)d_in[15];
  const float* teb  = (const float*)d_in[16];
  const float* wmem = (const float*)d_in[17];
  const float* wcw  = (const float*)d_in[18];
  const float* wcb  = (const float*)d_in[19];
  const float* ow1  = (const float*)d_in[20];
  const float* ob1  = (const float*)d_in[21];
  const float* ow2  = (const float*)d_in[22];
  const float* ob2  = (const float*)d_in[23];
  float* out = (float*)d_out;

  // workspace layout: 209.4 MB total (== Round-3-proven footprint)
  char* ws = (char*)d_ws;
  size_t off = 0;
  auto alloc = [&](size_t bytes) -> void* {
    void* p = ws + off;
    off = (off + bytes + 255) & ~(size_t)255;
    return p;
  };
  __hip_bfloat16* Xb    = (__hip_bfloat16*)alloc((size_t)T_ * E_ * 2);     // 25.17 MB
  __hip_bfloat16* Xlo   = (__hip_bfloat16*)alloc((size_t)T_ * E_ * 2);     // 25.17 MB
  __hip_bfloat16* rW1s  = (__hip_bfloat16*)alloc(512ull * 768 * 2);
  float* wtok  = (float*)alloc((size_t)T_ * 8 * 4);                        // logits then masked weights
  float* entp  = (float*)alloc(256);
  float* meanz = (float*)alloc(96ull * 256 * 4);
  float* reprs = (float*)alloc(96ull * 256 * 4);
  float* swp   = (float*)alloc(512);
  __hip_bfloat16* ow1t  = (__hip_bfloat16*)alloc((size_t)P_ * E_ * 2);
  __hip_bfloat16* ow2t  = (__hip_bfloat16*)alloc((size_t)P_ * P_ * 2);
  __hip_bfloat16* gW1t  = (__hip_bfloat16*)alloc(2ull * H_ * E_ * 2);
  __hip_bfloat16* gW2t  = (__hip_bfloat16*)alloc(2ull * H_ * H_ * 2);
  __hip_bfloat16* BfG   = (__hip_bfloat16*)alloc(256ull * 1024 * 2);       // [256,1024] gW3 pair
  __hip_bfloat16* lW1tP = (__hip_bfloat16*)alloc(3ull * 1024 * 256 * 2);   // 3 pairs [1024,256]
  __hip_bfloat16* BfL   = (__hip_bfloat16*)alloc(3ull * 256 * 1024 * 2);   // 3 pairs [256,1024]
  float* Ball  = (float*)alloc(2048 * 4);
  __hip_bfloat16* bufP  = (__hip_bfloat16*)alloc((size_t)T_ * 1024 * 2);   // 100.66 MB, reused 4x
  float* pred  = (float*)alloc((size_t)T_ * P_ * 4);                       // 50.33 MB

  // aliases inside Xlo (dead after router GEMM):
  __hip_bfloat16* gh1h  = Xlo;                                // [T/2,512] bf16 = 25.17 MB exact
  __hip_bfloat16* wghtB = Xlo;                                // [TBC,256] bf16 (end of pipeline)
  __hip_bfloat16* out1B = Xlo + (size_t)TBC_ * 256;

  // weight conversion descriptors
  ConvArgs ca;
  int d = 0;
  for (int s = 0; s < 2; ++s)
    ca.d[d++] = { gW1 + (size_t)s * E_ * H_, gW1t + (size_t)s * 512 * 256, E_, H_, 256, 0 };
  for (int s = 0; s < 2; ++s)
    ca.d[d++] = { gW2 + (size_t)s * H_ * H_, gW2t + (size_t)s * 512 * 512, H_, H_, 512, 0 };
  for (int s = 0; s < 2; ++s)
    ca.d[d++] = { gW3 + (size_t)s * H_ * P_, BfG, H_, P_, 1024, s * 512 };
  for (int e = 0; e < 6; ++e)
    ca.d[d++] = { lW1 + (size_t)e * E_ * H_, lW1tP + (size_t)(e >> 1) * 1024 * 256 + (size_t)(e & 1) * 512 * 256,
                  E_, H_, 256, 0 };
  for (int e = 0; e < 6; ++e)
    ca.d[d++] = { lW2 + (size_t)e * H_ * P_, BfL + (size_t)(e >> 1) * 256 * 1024, H_, P_, 1024, (e & 1) * 512 };
  ca.d[d++] = { ow1, ow1t, E_, P_, 256, 0 };
  ca.d[d++] = { ow2, ow2t, P_, P_, 256, 0 };

  // ---- prologue ----
  zero_wtok_kernel<<<384, 256, 0, stream>>>((float4*)wtok, entp);
  convert_x_kernel<<<1024, 256, 0, stream>>>(x, Xb, Xlo, T_ * E_ / 4);
  build_router_w_kernel<<<1536, 256, 0, stream>>>(rw1, rW1s);
  convert_wt_kernel<<<dim3(64, 20), 256, 0, stream>>>(ca);
  build_ball_kernel<<<8, 256, 0, stream>>>(gb3, lb2, Ball);

  // ---- router: split-bf16 GEMM with fused logits epilogue (no Hr buffer) ----
  gemm_bf16_k<8, true, true><<<dim3(T_ / 128, 4), 256, 0, stream>>>(
      Xb, rW1s, rb1, wtok, nullptr, T_, 512, 768, 0, Xlo, 256, 768, 0, rw2);
  logits_finish_kernel<<<T_ / 256, 256, 0, stream>>>(wtok, rb2, entp);

  // ---- global experts: L1 -> gh1h (T/2 chunks, aliases Xlo), L2 scaled -> bufP ----
  for (int s = 0; s < 2; ++s) {
    for (int half = 0; half < 2; ++half) {
      const size_t r0 = (size_t)half * (T_ / 2);
      gemm_bf16_k<0, true, false><<<dim3(T_ / 256, 4), 256, 0, stream>>>(
          Xb + r0 * 256, gW1t + (size_t)s * 512 * 256, gb1 + s * 512, gh1h, nullptr,
          T_ / 2, 512, 256, 0, nullptr, 256, 256, 512, nullptr);
      gemm_bf16_k<4, true, false><<<dim3(T_ / 256, 4), 256, 0, stream>>>(
          gh1h, gW2t + (size_t)s * 512 * 512, gb2 + s * 512, bufP + r0 * 1024 + s * 512,
          wtok + r0 * 8, T_ / 2, 512, 512, s, nullptr, 512, 512, 1024, nullptr);
    }
  }
  // global final: pred = bufP @ BfG + sum_e wtok[:,e]*Ball[e]
  gemm_bf16_k<6, true, false><<<dim3(T_ / 128, 2), 256, 0, stream>>>(
      bufP, BfG, nullptr, pred, wtok, T_, 256, 1024, 0, nullptr, 1024, 1024, 256, Ball);

  // ---- local experts: pair L1 (scaled, N=1024) -> bufP; pair final -> pred += ----
  for (int p = 0; p < 3; ++p) {
    gemm_bf16_k<4, true, false><<<dim3(T_ / 128, 8), 256, 0, stream>>>(
        Xb, lW1tP + (size_t)p * 1024 * 256, lb1 + p * 1024, bufP, wtok,
        T_, 1024, 256, 2 + 2 * p, nullptr, 256, 256, 1024, nullptr);
    gemm_bf16_k<6, false, false><<<dim3(T_ / 128, 2), 256, 0, stream>>>(
        bufP, BfL + (size_t)p * 256 * 1024, nullptr, pred, wtok,
        T_, 256, 1024, 0, nullptr, 1024, 1024, 256, nullptr);
  }

  // ---- tail ----
  mean_kernel<<<96, 256, 0, stream>>>(pred, meanz);
  te_kernel<<<96, 256, 0, stream>>>(meanz, tew, teb, reprs);
  wc_kernel<<<32, 128, 0, stream>>>(reprs, wmem, wcw, wcb, swp);
  weighted_kernel<<<TBC_, 256, 0, stream>>>(pred, swp, wghtB);

  gemm_bf16_k<0, true, false><<<dim3(TBC_ / 128, 2), 256, 0, stream>>>(
      wghtB, ow1t, ob1, out1B, nullptr, TBC_, 256, 256, 0, nullptr, 256, 256, 256, nullptr);
  gemm_bf16_k<2, true, false><<<dim3(TBC_ / 128, 2), 256, 0, stream>>>(
      out1B, ow2t, ob2, out, nullptr, TBC_, 256, 256, 0, nullptr, 256, 256, 256, nullptr);

  finalize_kernel<<<1, 1, 0, stream>>>(entp, out);
  (void)in_sizes; (void)n_in; (void)out_size; (void)ws_size;
}

// Round 9
// 945.601 us; speedup vs baseline: 1.1372x; 1.1372x over previous
//
#include <hip/hip_runtime.h>
#include <hip/hip_bf16.h>
#include <math.h>

// Problem constants (from reference)
#define S_   3
#define B_   32
#define C_   512
#define E_   256      // INPUT_DIM
#define H_   512      // HIDDEN_DIM
#define P_   256      // PRED_LEN
#define T_   49152    // S*B*C tokens (expert weights shared across scales -> flatten)
#define TBC_ 16384    // B*C

typedef __attribute__((ext_vector_type(8))) short v_s16x8;  // 8 bf16 (4 VGPR)
typedef __attribute__((ext_vector_type(4))) float v_f32x4;  // MFMA accumulator

__device__ __forceinline__ float gelu_f(float x) {
  // exact gelu (approximate=False): 0.5*x*(1+erf(x/sqrt(2)))
  return 0.5f * x * (1.0f + erff(x * 0.70710678118654752440f));
}

__device__ __forceinline__ void gload_lds16(const void* g, void* l) {
  // async global->LDS, 16B per lane; LDS dest = wave-uniform base + lane*16
  __builtin_amdgcn_global_load_lds((const __attribute__((address_space(1))) void*)g,
                                   (__attribute__((address_space(3))) void*)l, 16, 0, 0);
}

// ---------------------------------------------------------------------------
// bf16 MFMA GEMM, m97 structure: 128x128 tile, BK=32, 4 waves (2x2 of 64x64),
// 16x16x32 MFMA, global_load_lds width 16, 2 barriers per K-step.
// A [M,K] bf16 (row stride lda elems), Bt [N,K] bf16 (row stride ldb elems).
// SPLITA: A has 256 real cols; virtual K=768 = [A_hi | A_lo | A_hi]
//         (split-bf16 fp32-emulation: acc = hi*hi + lo*hi + hi*lo).
// MODE 0: bf16 gelu(acc+bias)
// MODE 2: f32 acc+bias
// MODE 3: f32 gelu(acc+bias)                                [router hidden]
// MODE 4: bf16 wtok[row][eidxBase+(col>>9)]*gelu(acc+bias)  [scaled hidden]
// MODE 6: f32 pred: STORE -> acc + sum_e wtok[row][e]*Ball[e*256+col]; else +=
// NOTE (R8 post-mortem): a MODE-8 variant fusing logits via global atomicAdd
// was measured at 256us (far-atomic RMW serialization, ~100MB HBM write from
// 3.1M atomics, MfmaUtil 6%). Reverted to MODE 3 + standalone logits kernel.
// ---------------------------------------------------------------------------
template<int MODE, bool STORE, bool SPLITA>
__global__ __launch_bounds__(256)
void gemm_bf16_k(const __hip_bfloat16* __restrict__ A,
                 const __hip_bfloat16* __restrict__ Bt,
                 const float* __restrict__ bias,
                 void* __restrict__ Cout,
                 const float* __restrict__ wtok,
                 int M, int N, int K, int eidxBase,
                 const __hip_bfloat16* __restrict__ Alo,
                 int lda, int ldb, int ldc,
                 const float* __restrict__ Ball)
{
  __shared__ __align__(16) unsigned short As[4096];  // [128][32] bf16
  __shared__ __align__(16) unsigned short Bs[4096];  // [128][32] bf16 (rows = out cols)
  __shared__ float BallS[(MODE == 6 && STORE) ? 2048 : 1];
  const int tid  = threadIdx.x;
  const int wid  = tid >> 6;
  const int lane = tid & 63;
  const int wm = wid >> 1, wn = wid & 1;
  const int l15 = lane & 15, l4 = lane >> 4;

  if constexpr (MODE == 6 && STORE) {
    for (int i = tid; i < 2048; i += 256) BallS[i] = Ball[i];  // 8 expert biases
    // first in-loop __syncthreads() makes these visible before epilogue use
  }

  v_f32x4 acc[4][4] = {};

  const size_t ArsB = (size_t)lda * 2;   // A row stride bytes
  const size_t BrsB = (size_t)ldb * 2;   // Bt row stride bytes
  const char* AgHi = (const char*)A + (size_t)blockIdx.x * 128 * ArsB;
  const char* AgLo = SPLITA ? ((const char*)Alo + (size_t)blockIdx.x * 128 * ArsB) : nullptr;
  const char* Bg   = (const char*)Bt + (size_t)blockIdx.y * 128 * BrsB;

  // staging geometry: 8KB per tile = 4 waves x 2 chunks x 64 lanes x 16B
  const int ob0 = (0 * 4 + wid) * 1024 + lane * 16;
  const int ob1 = (1 * 4 + wid) * 1024 + lane * 16;
  const int r0 = ob0 >> 6, kb0 = ob0 & 63;
  const int r1 = ob1 >> 6, kb1 = ob1 & 63;
  char* lA0 = (char*)As + (0 * 4 + wid) * 1024;
  char* lA1 = (char*)As + (1 * 4 + wid) * 1024;
  char* lB0 = (char*)Bs + (0 * 4 + wid) * 1024;
  char* lB1 = (char*)Bs + (1 * 4 + wid) * 1024;
  const size_t aoff0 = (size_t)r0 * ArsB + kb0;
  const size_t aoff1 = (size_t)r1 * ArsB + kb1;
  const char* gB0 = Bg + (size_t)r0 * BrsB + kb0;
  const char* gB1 = Bg + (size_t)r1 * BrsB + kb1;

  for (int kt = 0; kt < K; kt += 32) {
    const char* Asrc = AgHi;
    size_t akt = (size_t)kt * 2;
    if (SPLITA) {
      akt = (size_t)(kt & 255) * 2;
      if ((kt >> 8) == 1) Asrc = AgLo;
    }
    size_t bkt = (size_t)kt * 2;
    gload_lds16(Asrc + aoff0 + akt, lA0);
    gload_lds16(Asrc + aoff1 + akt, lA1);
    gload_lds16(gB0 + bkt, lB0);
    gload_lds16(gB1 + bkt, lB1);
    __syncthreads();   // vmcnt drain + barrier
    v_s16x8 af[4], bfv[4];
#pragma unroll
    for (int m = 0; m < 4; ++m)
      af[m] = *(const v_s16x8*)(As + (wm * 64 + m * 16 + l15) * 32 + l4 * 8);
#pragma unroll
    for (int n = 0; n < 4; ++n)
      bfv[n] = *(const v_s16x8*)(Bs + (wn * 64 + n * 16 + l15) * 32 + l4 * 8);
#pragma unroll
    for (int m = 0; m < 4; ++m)
#pragma unroll
      for (int n = 0; n < 4; ++n)
        acc[m][n] = __builtin_amdgcn_mfma_f32_16x16x32_bf16(af[m], bfv[n], acc[m][n], 0, 0, 0);
    __syncthreads();   // protect LDS before next stage
  }

  const int crow0 = blockIdx.x * 128 + wm * 64;
  const int ccol0 = blockIdx.y * 128 + wn * 64;

  if constexpr (MODE == 6) {
    // fused final accumulate: pred[row*ldc+col]
    float* P = (float*)Cout;
#pragma unroll
    for (int m = 0; m < 4; ++m) {
      float4 w0[4], w1[4];
      if (STORE) {
#pragma unroll
        for (int j = 0; j < 4; ++j) {
          const float4* wp = (const float4*)&wtok[(size_t)(crow0 + m * 16 + l4 * 4 + j) * 8];
          w0[j] = wp[0]; w1[j] = wp[1];
        }
      }
#pragma unroll
      for (int n = 0; n < 4; ++n) {
        const int col = ccol0 + n * 16 + l15;
        float bs[8];
        if (STORE) {
#pragma unroll
          for (int e = 0; e < 8; ++e) bs[e] = BallS[e * 256 + col];
        }
#pragma unroll
        for (int j = 0; j < 4; ++j) {
          const int row = crow0 + m * 16 + l4 * 4 + j;
          float v = acc[m][n][j];
          if (STORE) {
            v += bs[0] * w0[j].x + bs[1] * w0[j].y + bs[2] * w0[j].z + bs[3] * w0[j].w
               + bs[4] * w1[j].x + bs[5] * w1[j].y + bs[6] * w1[j].z + bs[7] * w1[j].w;
            P[(size_t)row * ldc + col] = v;
          } else {
            P[(size_t)row * ldc + col] += v;
          }
        }
      }
    }
    return;
  }

#pragma unroll
  for (int m = 0; m < 4; ++m) {
    float wv[4];
    if (MODE == 4) {
      const int e4 = eidxBase + (ccol0 >> 9);
#pragma unroll
      for (int j = 0; j < 4; ++j)
        wv[j] = wtok[(size_t)(crow0 + m * 16 + l4 * 4 + j) * 8 + e4];
    }
#pragma unroll
    for (int n = 0; n < 4; ++n) {
      const int col = ccol0 + n * 16 + l15;
      const float bv = bias[col];
#pragma unroll
      for (int j = 0; j < 4; ++j) {
        const int row = crow0 + m * 16 + l4 * 4 + j;
        float v = acc[m][n][j] + bv;
        if constexpr (MODE == 0) {
          ((__hip_bfloat16*)Cout)[(size_t)row * ldc + col] = __float2bfloat16(gelu_f(v));
        } else if constexpr (MODE == 2) {
          ((float*)Cout)[(size_t)row * ldc + col] = v;
        } else if constexpr (MODE == 3) {
          ((float*)Cout)[(size_t)row * ldc + col] = gelu_f(v);
        } else if constexpr (MODE == 4) {
          ((__hip_bfloat16*)Cout)[(size_t)row * ldc + col] = __float2bfloat16(wv[j] * gelu_f(v));
        }
      }
    }
  }
}

// ---------------------------------------------------------------------------
// logits/softmax/top-2/entropy: one token per thread (proven R3/R5 path).
// ---------------------------------------------------------------------------
__global__ __launch_bounds__(256) void logits_kernel(
    const float* __restrict__ hr,   // [T,512] fp32 gelu'd hidden
    const float* __restrict__ w2,   // [512,8]
    const float* __restrict__ b2,   // [8]
    float* __restrict__ wtok,       // [T,8]
    float* __restrict__ entp)       // [1]
{
  const int t = blockIdx.x * 256 + threadIdx.x;
  const float4* hrow = (const float4*)(hr + (size_t)t * 512);
  float lg[8];
#pragma unroll
  for (int e = 0; e < 8; ++e) lg[e] = b2[e];
#pragma unroll 4
  for (int k4 = 0; k4 < 128; ++k4) {
    float4 hv = hrow[k4];
    float hvv[4] = {hv.x, hv.y, hv.z, hv.w};
#pragma unroll
    for (int j = 0; j < 4; ++j) {
      const float* wr = w2 + (k4 * 4 + j) * 8;
#pragma unroll
      for (int e = 0; e < 8; ++e) lg[e] += hvv[j] * wr[e];
    }
  }
  float we[8];
  float mx = lg[0];
#pragma unroll
  for (int e = 1; e < 8; ++e) mx = fmaxf(mx, lg[e]);
  float ssum = 0.f;
#pragma unroll
  for (int e = 0; e < 8; ++e) { we[e] = expf(lg[e] - mx); ssum += we[e]; }
#pragma unroll
  for (int e = 0; e < 8; ++e) we[e] = we[e] / ssum;
  float ent = 0.f;
#pragma unroll
  for (int e = 0; e < 8; ++e) ent += we[e] * logf(we[e] + 1e-8f);
  // top-2 of locals (ties -> lower index, matching lax.top_k)
  int i1 = 0; float v1 = we[2];
#pragma unroll
  for (int n = 1; n < 6; ++n) if (we[2 + n] > v1) { v1 = we[2 + n]; i1 = n; }
  int i2 = -1; float v2 = -1e30f;
#pragma unroll
  for (int n = 0; n < 6; ++n) if (n != i1 && we[2 + n] > v2) { v2 = we[2 + n]; i2 = n; }
  float ow[8];
  ow[0] = we[0]; ow[1] = we[1];
#pragma unroll
  for (int n = 0; n < 6; ++n) ow[2 + n] = 0.f;
  ow[2 + i1] = v1; ow[2 + i2] = v2;
  float* wp = wtok + (size_t)t * 8;
#pragma unroll
  for (int e = 0; e < 8; ++e) wp[e] = ow[e];
  __shared__ float red[256];
  red[threadIdx.x] = ent;
  __syncthreads();
  for (int s = 128; s > 0; s >>= 1) {
    if (threadIdx.x < s) red[threadIdx.x] += red[threadIdx.x + s];
    __syncthreads();
  }
  if (threadIdx.x == 0) atomicAdd(entp, red[0]);
}

// ---------------------------------------------------------------------------
// small helper kernels
// ---------------------------------------------------------------------------
__global__ void zero_kernel(float* p) { p[0] = 0.f; }

__global__ void convert_x_kernel(const float* __restrict__ x,
                                 __hip_bfloat16* __restrict__ xb,
                                 __hip_bfloat16* __restrict__ xlo, int n4) {
  int stride = gridDim.x * blockDim.x;
  for (int i = blockIdx.x * blockDim.x + threadIdx.x; i < n4; i += stride) {
    float4 v = ((const float4*)x)[i];
    float vv[4] = {v.x, v.y, v.z, v.w};
    union { __hip_bfloat16 h[4]; ushort4 u; } hi, lo;
#pragma unroll
    for (int j = 0; j < 4; ++j) {
      hi.h[j] = __float2bfloat16(vv[j]);
      lo.h[j] = __float2bfloat16(vv[j] - __bfloat162float(hi.h[j]));
    }
    ((ushort4*)xb)[i] = hi.u;
    ((ushort4*)xlo)[i] = lo.u;
  }
}

// router W1 -> [N=512][K=768] bf16: cols 0..255 = W_hi, 256..511 = W_hi, 512..767 = W_lo
__global__ void build_router_w_kernel(const float* __restrict__ rw1,
                                      __hip_bfloat16* __restrict__ dst) {
  int i = blockIdx.x * 256 + threadIdx.x;   // 512*768 total
  int n = i / 768, k = i - n * 768;
  float src = rw1[(size_t)(k & 255) * 512 + n];
  __hip_bfloat16 hv = __float2bfloat16(src);
  dst[i] = (k < 512) ? hv : __float2bfloat16(src - __bfloat162float(hv));
}

// Ball[8][256] = [gb3_0;gb3_1;lb2_0..5]  (2048 floats, grid 8x256)
__global__ void build_ball_kernel(const float* __restrict__ gb3, const float* __restrict__ lb2,
                                  float* __restrict__ Ball) {
  int i = blockIdx.x * 256 + threadIdx.x;
  Ball[i] = (i < 512) ? gb3[i] : lb2[i - 512];
}

struct ConvDesc { const float* src; __hip_bfloat16* dst; int K; int N; int ldb; int koff; };
struct ConvArgs { ConvDesc d[20]; };

// dst[n*ldb + koff + k] = bf16(src[k*N+n]) : weight transpose+convert
__global__ void convert_wt_kernel(ConvArgs a) {
  ConvDesc c = a.d[blockIdx.y];
  int total = c.K * c.N;
  int stride = gridDim.x * blockDim.x;
  for (int e = blockIdx.x * blockDim.x + threadIdx.x; e < total; e += stride) {
    int n = e / c.K;
    int k = e - n * c.K;
    c.dst[(size_t)n * c.ldb + c.koff + k] = __float2bfloat16(c.src[(size_t)k * c.N + n]);
  }
}

// meanz[r][o] = mean_c pred[r*512+c][o], r = s*32+b
__global__ void mean_kernel(const float* __restrict__ pred, float* __restrict__ meanz) {
  int r = blockIdx.x, o = threadIdx.x;
  const float* p = pred + (size_t)r * 512 * 256 + o;
  float s0 = 0.f, s1 = 0.f, s2 = 0.f, s3 = 0.f;
  for (int c = 0; c < 512; c += 4) {
    s0 += p[(size_t)(c + 0) * 256]; s1 += p[(size_t)(c + 1) * 256];
    s2 += p[(size_t)(c + 2) * 256]; s3 += p[(size_t)(c + 3) * 256];
  }
  meanz[r * 256 + o] = (s0 + s1 + s2 + s3) * (1.0f / 512.0f);
}

__global__ void te_kernel(const float* __restrict__ meanz, const float* __restrict__ tw,
                          const float* __restrict__ tb, float* __restrict__ reprs) {
  __shared__ float row[256];
  int r = blockIdx.x, j = threadIdx.x;
  row[j] = meanz[r * 256 + j];
  __syncthreads();
  float a = 0.f;
  for (int k = 0; k < 256; ++k) a += row[k] * tw[k * 256 + j];
  reprs[r * 256 + j] = gelu_f(a + tb[j]);
}

__global__ void wc_kernel(const float* __restrict__ reprs, const float* __restrict__ wmem,
                          const float* __restrict__ wcw, const float* __restrict__ wcb,
                          float* __restrict__ sw) {
  __shared__ float red[128][3];
  int b = blockIdx.x, tid = threadIdx.x;
  float a0 = 0.f, a1 = 0.f, a2 = 0.f;
  for (int i = tid; i < 771; i += 128) {
    float cv = (i < 768) ? reprs[(i >> 8) * 8192 + b * 256 + (i & 255)] : wmem[i - 768];
    a0 += cv * wcw[i * 3 + 0]; a1 += cv * wcw[i * 3 + 1]; a2 += cv * wcw[i * 3 + 2];
  }
  red[tid][0] = a0; red[tid][1] = a1; red[tid][2] = a2;
  __syncthreads();
  for (int s = 64; s > 0; s >>= 1) {
    if (tid < s) {
      red[tid][0] += red[tid + s][0];
      red[tid][1] += red[tid + s][1];
      red[tid][2] += red[tid + s][2];
    }
    __syncthreads();
  }
  if (tid == 0) {
    float r[3]; float mx = -1e30f;
    for (int j = 0; j < 3; ++j) {
      float v = tanhf(red[0][j] + wcb[j]);
      r[j] = log1pf(expf(v));
      mx = fmaxf(mx, r[j]);
    }
    float s = 0.f;
    for (int j = 0; j < 3; ++j) { r[j] = expf(r[j] - mx); s += r[j]; }
    for (int j = 0; j < 3; ++j) sw[b * 3 + j] = r[j] / s;
  }
}

__global__ void weighted_kernel(const float* __restrict__ pred, const float* __restrict__ sw,
                                __hip_bfloat16* __restrict__ wb) {
  int t = blockIdx.x, o = threadIdx.x;
  int b = t >> 9;
  float s0 = sw[b * 3 + 0], s1 = sw[b * 3 + 1], s2 = sw[b * 3 + 2];
  size_t i = (size_t)t * 256 + o;
  float v = pred[i] * s0 + pred[i + (size_t)TBC_ * 256] * s1 + pred[i + (size_t)2 * TBC_ * 256] * s2;
  wb[i] = __float2bfloat16(v);
}

__global__ void finalize_kernel(const float* __restrict__ entp, float* __restrict__ out) {
  out[4194304] = -0.1f * entp[0] / 49152.0f;   // balance_loss = 0.1 * entropy
}

// ---------------------------------------------------------------------------
extern "C" void kernel_launch(void* const* d_in, const int* in_sizes, int n_in,
                              void* d_out, int out_size, void* d_ws, size_t ws_size,
                              hipStream_t stream) {
  const float* x    = (const float*)d_in[0];
  const float* rw1  = (const float*)d_in[1];
  const float* rb1  = (const float*)d_in[2];
  const float* rw2  = (const float*)d_in[3];
  const float* rb2  = (const float*)d_in[4];
  const float* gW1  = (const float*)d_in[5];
  const float* gb1  = (const float*)d_in[6];
  const float* gW2  = (const float*)d_in[7];
  const float* gb2  = (const float*)d_in[8];
  const float* gW3  = (const float*)d_in[9];
  const float* gb3  = (const float*)d_in[10];
  const float* lW1  = (const float*)d_in[11];
  const float* lb1  = (const float*)d_in[12];
  const float* lW2  = (const float*)d_in[13];
  const float* lb2  = (const float*)d_in[14];
  const float* tew  = (const float*)d_in[15];
  const float* teb  = (const float*)d_in[16];
  const float* wmem = (const float*)d_in[17];
  const float* wcw  = (const float*)d_in[18];
  const float* wcb  = (const float*)d_in[19];
  const float* ow1  = (const float*)d_in[20];
  const float* ob1  = (const float*)d_in[21];
  const float* ow2  = (const float*)d_in[22];
  const float* ob2  = (const float*)d_in[23];
  float* out = (float*)d_out;

  // workspace layout: ~209.4 MB total (== Round-3-proven footprint)
  char* ws = (char*)d_ws;
  size_t off = 0;
  auto alloc = [&](size_t bytes) -> void* {
    void* p = ws + off;
    off = (off + bytes + 255) & ~(size_t)255;
    return p;
  };
  __hip_bfloat16* Xb    = (__hip_bfloat16*)alloc((size_t)T_ * E_ * 2);     // 25.17 MB
  __hip_bfloat16* Xlo   = (__hip_bfloat16*)alloc((size_t)T_ * E_ * 2);     // 25.17 MB
  __hip_bfloat16* rW1s  = (__hip_bfloat16*)alloc(512ull * 768 * 2);
  float* wtok  = (float*)alloc((size_t)T_ * 8 * 4);
  float* entp  = (float*)alloc(256);
  float* meanz = (float*)alloc(96ull * 256 * 4);
  float* reprs = (float*)alloc(96ull * 256 * 4);
  float* swp   = (float*)alloc(512);
  __hip_bfloat16* ow1t  = (__hip_bfloat16*)alloc((size_t)P_ * E_ * 2);
  __hip_bfloat16* ow2t  = (__hip_bfloat16*)alloc((size_t)P_ * P_ * 2);
  __hip_bfloat16* gW1t  = (__hip_bfloat16*)alloc(2ull * H_ * E_ * 2);
  __hip_bfloat16* gW2t  = (__hip_bfloat16*)alloc(2ull * H_ * H_ * 2);
  __hip_bfloat16* BfG   = (__hip_bfloat16*)alloc(256ull * 1024 * 2);       // [256,1024] gW3 pair
  __hip_bfloat16* lW1tP = (__hip_bfloat16*)alloc(3ull * 1024 * 256 * 2);   // 3 pairs [1024,256]
  __hip_bfloat16* BfL   = (__hip_bfloat16*)alloc(3ull * 256 * 1024 * 2);   // 3 pairs [256,1024]
  float* Ball  = (float*)alloc(2048 * 4);
  __hip_bfloat16* bufP  = (__hip_bfloat16*)alloc((size_t)T_ * 1024 * 2);   // 100.66 MB, reused 4x
  float* pred  = (float*)alloc((size_t)T_ * P_ * 4);                       // 50.33 MB

  // aliases:
  // Hr (router hidden fp32 [T,512] = 100,663,296 B) aliases bufP exactly:
  //   written by router GEMM, read by logits_kernel, dead before first
  //   expert L2 write into bufP (same stream, serialized).
  float* Hr = (float*)bufP;
  // inside Xlo (dead after router GEMM reads it as Alo):
  __hip_bfloat16* gh1h  = Xlo;                                // [T/2,512] bf16 = 25.17 MB exact
  __hip_bfloat16* wghtB = Xlo;                                // [TBC,256] bf16 (end of pipeline)
  __hip_bfloat16* out1B = Xlo + (size_t)TBC_ * 256;

  // weight conversion descriptors
  ConvArgs ca;
  int d = 0;
  for (int s = 0; s < 2; ++s)
    ca.d[d++] = { gW1 + (size_t)s * E_ * H_, gW1t + (size_t)s * 512 * 256, E_, H_, 256, 0 };
  for (int s = 0; s < 2; ++s)
    ca.d[d++] = { gW2 + (size_t)s * H_ * H_, gW2t + (size_t)s * 512 * 512, H_, H_, 512, 0 };
  for (int s = 0; s < 2; ++s)
    ca.d[d++] = { gW3 + (size_t)s * H_ * P_, BfG, H_, P_, 1024, s * 512 };
  for (int e = 0; e < 6; ++e)
    ca.d[d++] = { lW1 + (size_t)e * E_ * H_, lW1tP + (size_t)(e >> 1) * 1024 * 256 + (size_t)(e & 1) * 512 * 256,
                  E_, H_, 256, 0 };
  for (int e = 0; e < 6; ++e)
    ca.d[d++] = { lW2 + (size_t)e * H_ * P_, BfL + (size_t)(e >> 1) * 256 * 1024, H_, P_, 1024, (e & 1) * 512 };
  ca.d[d++] = { ow1, ow1t, E_, P_, 256, 0 };
  ca.d[d++] = { ow2, ow2t, P_, P_, 256, 0 };

  // ---- prologue ----
  zero_kernel<<<1, 1, 0, stream>>>(entp);
  convert_x_kernel<<<1024, 256, 0, stream>>>(x, Xb, Xlo, T_ * E_ / 4);
  build_router_w_kernel<<<1536, 256, 0, stream>>>(rw1, rW1s);
  convert_wt_kernel<<<dim3(64, 20), 256, 0, stream>>>(ca);
  build_ball_kernel<<<8, 256, 0, stream>>>(gb3, lb2, Ball);

  // ---- router: split-bf16 GEMM (MODE 3, fp32 Hr) + standalone logits ----
  gemm_bf16_k<3, true, true><<<dim3(T_ / 128, 4), 256, 0, stream>>>(
      Xb, rW1s, rb1, Hr, nullptr, T_, 512, 768, 0, Xlo, 256, 768, 512, nullptr);
  logits_kernel<<<T_ / 256, 256, 0, stream>>>(Hr, rw2, rb2, wtok, entp);

  // ---- global experts: L1 -> gh1h (T/2 chunks, aliases Xlo), L2 scaled -> bufP ----
  for (int s = 0; s < 2; ++s) {
    for (int half = 0; half < 2; ++half) {
      const size_t r0 = (size_t)half * (T_ / 2);
      gemm_bf16_k<0, true, false><<<dim3(T_ / 256, 4), 256, 0, stream>>>(
          Xb + r0 * 256, gW1t + (size_t)s * 512 * 256, gb1 + s * 512, gh1h, nullptr,
          T_ / 2, 512, 256, 0, nullptr, 256, 256, 512, nullptr);
      gemm_bf16_k<4, true, false><<<dim3(T_ / 256, 4), 256, 0, stream>>>(
          gh1h, gW2t + (size_t)s * 512 * 512, gb2 + s * 512, bufP + r0 * 1024 + s * 512,
          wtok + r0 * 8, T_ / 2, 512, 512, s, nullptr, 512, 512, 1024, nullptr);
    }
  }
  // global final: pred = bufP @ BfG + sum_e wtok[:,e]*Ball[e]
  gemm_bf16_k<6, true, false><<<dim3(T_ / 128, 2), 256, 0, stream>>>(
      bufP, BfG, nullptr, pred, wtok, T_, 256, 1024, 0, nullptr, 1024, 1024, 256, Ball);

  // ---- local experts: pair L1 (scaled, N=1024) -> bufP; pair final -> pred += ----
  for (int p = 0; p < 3; ++p) {
    gemm_bf16_k<4, true, false><<<dim3(T_ / 128, 8), 256, 0, stream>>>(
        Xb, lW1tP + (size_t)p * 1024 * 256, lb1 + p * 1024, bufP, wtok,
        T_, 1024, 256, 2 + 2 * p, nullptr, 256, 256, 1024, nullptr);
    gemm_bf16_k<6, false, false><<<dim3(T_ / 128, 2), 256, 0, stream>>>(
        bufP, BfL + (size_t)p * 256 * 1024, nullptr, pred, wtok,
        T_, 256, 1024, 0, nullptr, 1024, 1024, 256, nullptr);
  }

  // ---- tail ----
  mean_kernel<<<96, 256, 0, stream>>>(pred, meanz);
  te_kernel<<<96, 256, 0, stream>>>(meanz, tew, teb, reprs);
  wc_kernel<<<32, 128, 0, stream>>>(reprs, wmem, wcw, wcb, swp);
  weighted_kernel<<<TBC_, 256, 0, stream>>>(pred, swp, wghtB);

  gemm_bf16_k<0, true, false><<<dim3(TBC_ / 128, 2), 256, 0, stream>>>(
      wghtB, ow1t, ob1, out1B, nullptr, TBC_, 256, 256, 0, nullptr, 256, 256, 256, nullptr);
  gemm_bf16_k<2, true, false><<<dim3(TBC_ / 128, 2), 256, 0, stream>>>(
      out1B, ow2t, ob2, out, nullptr, TBC_, 256, 256, 0, nullptr, 256, 256, 256, nullptr);

  finalize_kernel<<<1, 1, 0, stream>>>(entp, out);
  (void)in_sizes; (void)n_in; (void)out_size; (void)ws_size;
}

// Round 10
// 902.920 us; speedup vs baseline: 1.1910x; 1.0473x over previous
//
#include <hip/hip_runtime.h>
#include <hip/hip_bf16.h>
#include <math.h>

// Problem constants (from reference)
#define S_   3
#define B_   32
#define C_   512
#define E_   256      // INPUT_DIM
#define H_   512      // HIDDEN_DIM
#define P_   256      // PRED_LEN
#define T_   49152    // S*B*C tokens (expert weights shared across scales -> flatten)
#define TBC_ 16384    // B*C

typedef __attribute__((ext_vector_type(8))) short v_s16x8;  // 8 bf16 (4 VGPR)
typedef __attribute__((ext_vector_type(4))) float v_f32x4;  // MFMA accumulator

__device__ __forceinline__ float gelu_f(float x) {
  // exact gelu (approximate=False): 0.5*x*(1+erf(x/sqrt(2)))
  return 0.5f * x * (1.0f + erff(x * 0.70710678118654752440f));
}

__device__ __forceinline__ void gload_lds16(const void* g, void* l) {
  // async global->LDS, 16B per lane; LDS dest = wave-uniform base + lane*16
  __builtin_amdgcn_global_load_lds((const __attribute__((address_space(1))) void*)g,
                                   (__attribute__((address_space(3))) void*)l, 16, 0, 0);
}

// ---------------------------------------------------------------------------
// bf16 MFMA GEMM: 128x128 tile, BK=32, 4 waves (2x2 of 64x64), 16x16x32 MFMA,
// global_load_lds width 16.
// R10: T3-minimal double-buffered K-loop — stage tile k+1 into buf^1 BEFORE
// computing tile k, ONE barrier per K-step (was 2). Staging latency hides
// under ds_read+MFMA; __syncthreads' implicit vmcnt(0) drains the prefetch.
// A [M,K] bf16 (row stride lda elems), Bt [N,K] bf16 (row stride ldb elems).
// SPLITA: A has 256 real cols; virtual K=768 = [A_hi | A_lo | A_hi]
//         (split-bf16 fp32-emulation: acc = hi*hi + lo*hi + hi*lo).
// MODE 0: bf16 gelu(acc+bias)
// MODE 2: f32 acc+bias
// MODE 3: f32 gelu(acc+bias)                                [router hidden]
// MODE 4: bf16 wtok[row][eidxBase+(col>>9)]*gelu(acc+bias)  [scaled hidden]
// MODE 6: f32 pred: STORE -> acc + sum_e wtok[row][e]*Ball[e*256+col]; else +=
// NOTE (R8 post-mortem): a MODE-8 variant fusing logits via global atomicAdd
// measured 256us (far-atomic RMW serialization, ~100MB HBM write from 3.1M
// atomics, MfmaUtil 6%). Keep logits as a standalone kernel.
// ---------------------------------------------------------------------------
template<int MODE, bool STORE, bool SPLITA>
__global__ __launch_bounds__(256)
void gemm_bf16_k(const __hip_bfloat16* __restrict__ A,
                 const __hip_bfloat16* __restrict__ Bt,
                 const float* __restrict__ bias,
                 void* __restrict__ Cout,
                 const float* __restrict__ wtok,
                 int M, int N, int K, int eidxBase,
                 const __hip_bfloat16* __restrict__ Alo,
                 int lda, int ldb, int ldc,
                 const float* __restrict__ Ball)
{
  __shared__ __align__(16) unsigned short As[8192];  // 2 x [128][32] bf16 (dbuf)
  __shared__ __align__(16) unsigned short Bs[8192];  // 2 x [128][32] bf16
  __shared__ float BallS[(MODE == 6 && STORE) ? 2048 : 1];
  const int tid  = threadIdx.x;
  const int wid  = tid >> 6;
  const int lane = tid & 63;
  const int wm = wid >> 1, wn = wid & 1;
  const int l15 = lane & 15, l4 = lane >> 4;

  if constexpr (MODE == 6 && STORE) {
    for (int i = tid; i < 2048; i += 256) BallS[i] = Ball[i];  // 8 expert biases
    // prologue __syncthreads() makes these visible before epilogue use
  }

  v_f32x4 acc[4][4] = {};

  const size_t ArsB = (size_t)lda * 2;   // A row stride bytes
  const size_t BrsB = (size_t)ldb * 2;   // Bt row stride bytes
  const char* AgHi = (const char*)A + (size_t)blockIdx.x * 128 * ArsB;
  const char* AgLo = SPLITA ? ((const char*)Alo + (size_t)blockIdx.x * 128 * ArsB) : nullptr;
  const char* Bg   = (const char*)Bt + (size_t)blockIdx.y * 128 * BrsB;

  // staging geometry: 8KB per tile = 4 waves x 2 chunks x 64 lanes x 16B
  const int ob0 = (0 * 4 + wid) * 1024 + lane * 16;
  const int ob1 = (1 * 4 + wid) * 1024 + lane * 16;
  const int r0 = ob0 >> 6, kb0 = ob0 & 63;
  const int r1 = ob1 >> 6, kb1 = ob1 & 63;
  char* lA0 = (char*)As + (0 * 4 + wid) * 1024;
  char* lA1 = (char*)As + (1 * 4 + wid) * 1024;
  char* lB0 = (char*)Bs + (0 * 4 + wid) * 1024;
  char* lB1 = (char*)Bs + (1 * 4 + wid) * 1024;
  const size_t aoff0 = (size_t)r0 * ArsB + kb0;
  const size_t aoff1 = (size_t)r1 * ArsB + kb1;
  const char* gB0 = Bg + (size_t)r0 * BrsB + kb0;
  const char* gB1 = Bg + (size_t)r1 * BrsB + kb1;

  auto stage = [&](int kt, int bsel) {
    const char* Asrc = AgHi;
    size_t akt = (size_t)kt * 2;
    if (SPLITA) {
      akt = (size_t)(kt & 255) * 2;
      if ((kt >> 8) == 1) Asrc = AgLo;
    }
    const size_t bkt = (size_t)kt * 2;
    const int bo = bsel * 8192;           // bytes: 4096 ushorts per buffer
    gload_lds16(Asrc + aoff0 + akt, lA0 + bo);
    gload_lds16(Asrc + aoff1 + akt, lA1 + bo);
    gload_lds16(gB0 + bkt, lB0 + bo);
    gload_lds16(gB1 + bkt, lB1 + bo);
  };

  // prologue: stage first tile into buf 0
  stage(0, 0);
  __syncthreads();   // drain prologue stage (+ BallS visibility)

  for (int kt = 0; kt < K; kt += 32) {
    const int cur = (kt >> 5) & 1;
    if (kt + 32 < K) stage(kt + 32, cur ^ 1);   // prefetch next tile (async)
    const unsigned short* Ab = As + cur * 4096;
    const unsigned short* Bb = Bs + cur * 4096;
    v_s16x8 af[4], bfv[4];
#pragma unroll
    for (int m = 0; m < 4; ++m)
      af[m] = *(const v_s16x8*)(Ab + (wm * 64 + m * 16 + l15) * 32 + l4 * 8);
#pragma unroll
    for (int n = 0; n < 4; ++n)
      bfv[n] = *(const v_s16x8*)(Bb + (wn * 64 + n * 16 + l15) * 32 + l4 * 8);
#pragma unroll
    for (int m = 0; m < 4; ++m)
#pragma unroll
      for (int n = 0; n < 4; ++n)
        acc[m][n] = __builtin_amdgcn_mfma_f32_16x16x32_bf16(af[m], bfv[n], acc[m][n], 0, 0, 0);
    // ONE barrier per K-step: implicit vmcnt(0) drains the prefetch issued
    // above (which flew during ds_read+MFMA); all waves done reading buf[cur]
    // so next iteration may overwrite it.
    __syncthreads();
  }

  const int crow0 = blockIdx.x * 128 + wm * 64;
  const int ccol0 = blockIdx.y * 128 + wn * 64;

  if constexpr (MODE == 6) {
    // fused final accumulate: pred[row*ldc+col]
    float* P = (float*)Cout;
#pragma unroll
    for (int m = 0; m < 4; ++m) {
      float4 w0[4], w1[4];
      if (STORE) {
#pragma unroll
        for (int j = 0; j < 4; ++j) {
          const float4* wp = (const float4*)&wtok[(size_t)(crow0 + m * 16 + l4 * 4 + j) * 8];
          w0[j] = wp[0]; w1[j] = wp[1];
        }
      }
#pragma unroll
      for (int n = 0; n < 4; ++n) {
        const int col = ccol0 + n * 16 + l15;
        float bs[8];
        if (STORE) {
#pragma unroll
          for (int e = 0; e < 8; ++e) bs[e] = BallS[e * 256 + col];
        }
#pragma unroll
        for (int j = 0; j < 4; ++j) {
          const int row = crow0 + m * 16 + l4 * 4 + j;
          float v = acc[m][n][j];
          if (STORE) {
            v += bs[0] * w0[j].x + bs[1] * w0[j].y + bs[2] * w0[j].z + bs[3] * w0[j].w
               + bs[4] * w1[j].x + bs[5] * w1[j].y + bs[6] * w1[j].z + bs[7] * w1[j].w;
            P[(size_t)row * ldc + col] = v;
          } else {
            P[(size_t)row * ldc + col] += v;
          }
        }
      }
    }
    return;
  }

#pragma unroll
  for (int m = 0; m < 4; ++m) {
    float wv[4];
    if (MODE == 4) {
      const int e4 = eidxBase + (ccol0 >> 9);
#pragma unroll
      for (int j = 0; j < 4; ++j)
        wv[j] = wtok[(size_t)(crow0 + m * 16 + l4 * 4 + j) * 8 + e4];
    }
#pragma unroll
    for (int n = 0; n < 4; ++n) {
      const int col = ccol0 + n * 16 + l15;
      const float bv = bias[col];
#pragma unroll
      for (int j = 0; j < 4; ++j) {
        const int row = crow0 + m * 16 + l4 * 4 + j;
        float v = acc[m][n][j] + bv;
        if constexpr (MODE == 0) {
          ((__hip_bfloat16*)Cout)[(size_t)row * ldc + col] = __float2bfloat16(gelu_f(v));
        } else if constexpr (MODE == 2) {
          ((float*)Cout)[(size_t)row * ldc + col] = v;
        } else if constexpr (MODE == 3) {
          ((float*)Cout)[(size_t)row * ldc + col] = gelu_f(v);
        } else if constexpr (MODE == 4) {
          ((__hip_bfloat16*)Cout)[(size_t)row * ldc + col] = __float2bfloat16(wv[j] * gelu_f(v));
        }
      }
    }
  }
}

// ---------------------------------------------------------------------------
// logits/softmax/top-2/entropy: one token per thread (proven R3/R5 path).
// ---------------------------------------------------------------------------
__global__ __launch_bounds__(256) void logits_kernel(
    const float* __restrict__ hr,   // [T,512] fp32 gelu'd hidden
    const float* __restrict__ w2,   // [512,8]
    const float* __restrict__ b2,   // [8]
    float* __restrict__ wtok,       // [T,8]
    float* __restrict__ entp)       // [1]
{
  const int t = blockIdx.x * 256 + threadIdx.x;
  const float4* hrow = (const float4*)(hr + (size_t)t * 512);
  float lg[8];
#pragma unroll
  for (int e = 0; e < 8; ++e) lg[e] = b2[e];
#pragma unroll 4
  for (int k4 = 0; k4 < 128; ++k4) {
    float4 hv = hrow[k4];
    float hvv[4] = {hv.x, hv.y, hv.z, hv.w};
#pragma unroll
    for (int j = 0; j < 4; ++j) {
      const float* wr = w2 + (k4 * 4 + j) * 8;
#pragma unroll
      for (int e = 0; e < 8; ++e) lg[e] += hvv[j] * wr[e];
    }
  }
  float we[8];
  float mx = lg[0];
#pragma unroll
  for (int e = 1; e < 8; ++e) mx = fmaxf(mx, lg[e]);
  float ssum = 0.f;
#pragma unroll
  for (int e = 0; e < 8; ++e) { we[e] = expf(lg[e] - mx); ssum += we[e]; }
#pragma unroll
  for (int e = 0; e < 8; ++e) we[e] = we[e] / ssum;
  float ent = 0.f;
#pragma unroll
  for (int e = 0; e < 8; ++e) ent += we[e] * logf(we[e] + 1e-8f);
  // top-2 of locals (ties -> lower index, matching lax.top_k)
  int i1 = 0; float v1 = we[2];
#pragma unroll
  for (int n = 1; n < 6; ++n) if (we[2 + n] > v1) { v1 = we[2 + n]; i1 = n; }
  int i2 = -1; float v2 = -1e30f;
#pragma unroll
  for (int n = 0; n < 6; ++n) if (n != i1 && we[2 + n] > v2) { v2 = we[2 + n]; i2 = n; }
  float ow[8];
  ow[0] = we[0]; ow[1] = we[1];
#pragma unroll
  for (int n = 0; n < 6; ++n) ow[2 + n] = 0.f;
  ow[2 + i1] = v1; ow[2 + i2] = v2;
  float* wp = wtok + (size_t)t * 8;
#pragma unroll
  for (int e = 0; e < 8; ++e) wp[e] = ow[e];
  __shared__ float red[256];
  red[threadIdx.x] = ent;
  __syncthreads();
  for (int s = 128; s > 0; s >>= 1) {
    if (threadIdx.x < s) red[threadIdx.x] += red[threadIdx.x + s];
    __syncthreads();
  }
  if (threadIdx.x == 0) atomicAdd(entp, red[0]);
}

// ---------------------------------------------------------------------------
// small helper kernels
// ---------------------------------------------------------------------------
__global__ void zero_kernel(float* p) { p[0] = 0.f; }

__global__ void convert_x_kernel(const float* __restrict__ x,
                                 __hip_bfloat16* __restrict__ xb,
                                 __hip_bfloat16* __restrict__ xlo, int n4) {
  int stride = gridDim.x * blockDim.x;
  for (int i = blockIdx.x * blockDim.x + threadIdx.x; i < n4; i += stride) {
    float4 v = ((const float4*)x)[i];
    float vv[4] = {v.x, v.y, v.z, v.w};
    union { __hip_bfloat16 h[4]; ushort4 u; } hi, lo;
#pragma unroll
    for (int j = 0; j < 4; ++j) {
      hi.h[j] = __float2bfloat16(vv[j]);
      lo.h[j] = __float2bfloat16(vv[j] - __bfloat162float(hi.h[j]));
    }
    ((ushort4*)xb)[i] = hi.u;
    ((ushort4*)xlo)[i] = lo.u;
  }
}

// router W1 -> [N=512][K=768] bf16: cols 0..255 = W_hi, 256..511 = W_hi, 512..767 = W_lo
__global__ void build_router_w_kernel(const float* __restrict__ rw1,
                                      __hip_bfloat16* __restrict__ dst) {
  int i = blockIdx.x * 256 + threadIdx.x;   // 512*768 total
  int n = i / 768, k = i - n * 768;
  float src = rw1[(size_t)(k & 255) * 512 + n];
  __hip_bfloat16 hv = __float2bfloat16(src);
  dst[i] = (k < 512) ? hv : __float2bfloat16(src - __bfloat162float(hv));
}

// Ball[8][256] = [gb3_0;gb3_1;lb2_0..5]  (2048 floats, grid 8x256)
__global__ void build_ball_kernel(const float* __restrict__ gb3, const float* __restrict__ lb2,
                                  float* __restrict__ Ball) {
  int i = blockIdx.x * 256 + threadIdx.x;
  Ball[i] = (i < 512) ? gb3[i] : lb2[i - 512];
}

struct ConvDesc { const float* src; __hip_bfloat16* dst; int K; int N; int ldb; int koff; };
struct ConvArgs { ConvDesc d[20]; };

// dst[n*ldb + koff + k] = bf16(src[k*N+n]) : weight transpose+convert
__global__ void convert_wt_kernel(ConvArgs a) {
  ConvDesc c = a.d[blockIdx.y];
  int total = c.K * c.N;
  int stride = gridDim.x * blockDim.x;
  for (int e = blockIdx.x * blockDim.x + threadIdx.x; e < total; e += stride) {
    int n = e / c.K;
    int k = e - n * c.K;
    c.dst[(size_t)n * c.ldb + c.koff + k] = __float2bfloat16(c.src[(size_t)k * c.N + n]);
  }
}

// meanz[r][o] = mean_c pred[r*512+c][o], r = s*32+b
__global__ void mean_kernel(const float* __restrict__ pred, float* __restrict__ meanz) {
  int r = blockIdx.x, o = threadIdx.x;
  const float* p = pred + (size_t)r * 512 * 256 + o;
  float s0 = 0.f, s1 = 0.f, s2 = 0.f, s3 = 0.f;
  for (int c = 0; c < 512; c += 4) {
    s0 += p[(size_t)(c + 0) * 256]; s1 += p[(size_t)(c + 1) * 256];
    s2 += p[(size_t)(c + 2) * 256]; s3 += p[(size_t)(c + 3) * 256];
  }
  meanz[r * 256 + o] = (s0 + s1 + s2 + s3) * (1.0f / 512.0f);
}

__global__ void te_kernel(const float* __restrict__ meanz, const float* __restrict__ tw,
                          const float* __restrict__ tb, float* __restrict__ reprs) {
  __shared__ float row[256];
  int r = blockIdx.x, j = threadIdx.x;
  row[j] = meanz[r * 256 + j];
  __syncthreads();
  float a = 0.f;
  for (int k = 0; k < 256; ++k) a += row[k] * tw[k * 256 + j];
  reprs[r * 256 + j] = gelu_f(a + tb[j]);
}

__global__ void wc_kernel(const float* __restrict__ reprs, const float* __restrict__ wmem,
                          const float* __restrict__ wcw, const float* __restrict__ wcb,
                          float* __restrict__ sw) {
  __shared__ float red[128][3];
  int b = blockIdx.x, tid = threadIdx.x;
  float a0 = 0.f, a1 = 0.f, a2 = 0.f;
  for (int i = tid; i < 771; i += 128) {
    float cv = (i < 768) ? reprs[(i >> 8) * 8192 + b * 256 + (i & 255)] : wmem[i - 768];
    a0 += cv * wcw[i * 3 + 0]; a1 += cv * wcw[i * 3 + 1]; a2 += cv * wcw[i * 3 + 2];
  }
  red[tid][0] = a0; red[tid][1] = a1; red[tid][2] = a2;
  __syncthreads();
  for (int s = 64; s > 0; s >>= 1) {
    if (tid < s) {
      red[tid][0] += red[tid + s][0];
      red[tid][1] += red[tid + s][1];
      red[tid][2] += red[tid + s][2];
    }
    __syncthreads();
  }
  if (tid == 0) {
    float r[3]; float mx = -1e30f;
    for (int j = 0; j < 3; ++j) {
      float v = tanhf(red[0][j] + wcb[j]);
      r[j] = log1pf(expf(v));
      mx = fmaxf(mx, r[j]);
    }
    float s = 0.f;
    for (int j = 0; j < 3; ++j) { r[j] = expf(r[j] - mx); s += r[j]; }
    for (int j = 0; j < 3; ++j) sw[b * 3 + j] = r[j] / s;
  }
}

__global__ void weighted_kernel(const float* __restrict__ pred, const float* __restrict__ sw,
                                __hip_bfloat16* __restrict__ wb) {
  int t = blockIdx.x, o = threadIdx.x;
  int b = t >> 9;
  float s0 = sw[b * 3 + 0], s1 = sw[b * 3 + 1], s2 = sw[b * 3 + 2];
  size_t i = (size_t)t * 256 + o;
  float v = pred[i] * s0 + pred[i + (size_t)TBC_ * 256] * s1 + pred[i + (size_t)2 * TBC_ * 256] * s2;
  wb[i] = __float2bfloat16(v);
}

__global__ void finalize_kernel(const float* __restrict__ entp, float* __restrict__ out) {
  out[4194304] = -0.1f * entp[0] / 49152.0f;   // balance_loss = 0.1 * entropy
}

// ---------------------------------------------------------------------------
extern "C" void kernel_launch(void* const* d_in, const int* in_sizes, int n_in,
                              void* d_out, int out_size, void* d_ws, size_t ws_size,
                              hipStream_t stream) {
  const float* x    = (const float*)d_in[0];
  const float* rw1  = (const float*)d_in[1];
  const float* rb1  = (const float*)d_in[2];
  const float* rw2  = (const float*)d_in[3];
  const float* rb2  = (const float*)d_in[4];
  const float* gW1  = (const float*)d_in[5];
  const float* gb1  = (const float*)d_in[6];
  const float* gW2  = (const float*)d_in[7];
  const float* gb2  = (const float*)d_in[8];
  const float* gW3  = (const float*)d_in[9];
  const float* gb3  = (const float*)d_in[10];
  const float* lW1  = (const float*)d_in[11];
  const float* lb1  = (const float*)d_in[12];
  const float* lW2  = (const float*)d_in[13];
  const float* lb2  = (const float*)d_in[14];
  const float* tew  = (const float*)d_in[15];
  const float* teb  = (const float*)d_in[16];
  const float* wmem = (const float*)d_in[17];
  const float* wcw  = (const float*)d_in[18];
  const float* wcb  = (const float*)d_in[19];
  const float* ow1  = (const float*)d_in[20];
  const float* ob1  = (const float*)d_in[21];
  const float* ow2  = (const float*)d_in[22];
  const float* ob2  = (const float*)d_in[23];
  float* out = (float*)d_out;

  // workspace layout: ~209.4 MB total (== Round-3-proven footprint)
  char* ws = (char*)d_ws;
  size_t off = 0;
  auto alloc = [&](size_t bytes) -> void* {
    void* p = ws + off;
    off = (off + bytes + 255) & ~(size_t)255;
    return p;
  };
  __hip_bfloat16* Xb    = (__hip_bfloat16*)alloc((size_t)T_ * E_ * 2);     // 25.17 MB
  __hip_bfloat16* Xlo   = (__hip_bfloat16*)alloc((size_t)T_ * E_ * 2);     // 25.17 MB
  __hip_bfloat16* rW1s  = (__hip_bfloat16*)alloc(512ull * 768 * 2);
  float* wtok  = (float*)alloc((size_t)T_ * 8 * 4);
  float* entp  = (float*)alloc(256);
  float* meanz = (float*)alloc(96ull * 256 * 4);
  float* reprs = (float*)alloc(96ull * 256 * 4);
  float* swp   = (float*)alloc(512);
  __hip_bfloat16* ow1t  = (__hip_bfloat16*)alloc((size_t)P_ * E_ * 2);
  __hip_bfloat16* ow2t  = (__hip_bfloat16*)alloc((size_t)P_ * P_ * 2);
  __hip_bfloat16* gW1t  = (__hip_bfloat16*)alloc(2ull * H_ * E_ * 2);
  __hip_bfloat16* gW2t  = (__hip_bfloat16*)alloc(2ull * H_ * H_ * 2);
  __hip_bfloat16* BfG   = (__hip_bfloat16*)alloc(256ull * 1024 * 2);       // [256,1024] gW3 pair
  __hip_bfloat16* lW1tP = (__hip_bfloat16*)alloc(3ull * 1024 * 256 * 2);   // 3 pairs [1024,256]
  __hip_bfloat16* BfL   = (__hip_bfloat16*)alloc(3ull * 256 * 1024 * 2);   // 3 pairs [256,1024]
  float* Ball  = (float*)alloc(2048 * 4);
  __hip_bfloat16* bufP  = (__hip_bfloat16*)alloc((size_t)T_ * 1024 * 2);   // 100.66 MB, reused 4x
  float* pred  = (float*)alloc((size_t)T_ * P_ * 4);                       // 50.33 MB

  // aliases:
  // Hr (router hidden fp32 [T,512] = 100,663,296 B) aliases bufP exactly:
  //   written by router GEMM, read by logits_kernel, dead before first
  //   expert L2 write into bufP (same stream, serialized).
  float* Hr = (float*)bufP;
  // inside Xlo (dead after router GEMM reads it as Alo):
  __hip_bfloat16* gh1h  = Xlo;                                // [T/2,512] bf16 = 25.17 MB exact
  __hip_bfloat16* wghtB = Xlo;                                // [TBC,256] bf16 (end of pipeline)
  __hip_bfloat16* out1B = Xlo + (size_t)TBC_ * 256;

  // weight conversion descriptors
  ConvArgs ca;
  int d = 0;
  for (int s = 0; s < 2; ++s)
    ca.d[d++] = { gW1 + (size_t)s * E_ * H_, gW1t + (size_t)s * 512 * 256, E_, H_, 256, 0 };
  for (int s = 0; s < 2; ++s)
    ca.d[d++] = { gW2 + (size_t)s * H_ * H_, gW2t + (size_t)s * 512 * 512, H_, H_, 512, 0 };
  for (int s = 0; s < 2; ++s)
    ca.d[d++] = { gW3 + (size_t)s * H_ * P_, BfG, H_, P_, 1024, s * 512 };
  for (int e = 0; e < 6; ++e)
    ca.d[d++] = { lW1 + (size_t)e * E_ * H_, lW1tP + (size_t)(e >> 1) * 1024 * 256 + (size_t)(e & 1) * 512 * 256,
                  E_, H_, 256, 0 };
  for (int e = 0; e < 6; ++e)
    ca.d[d++] = { lW2 + (size_t)e * H_ * P_, BfL + (size_t)(e >> 1) * 256 * 1024, H_, P_, 1024, (e & 1) * 512 };
  ca.d[d++] = { ow1, ow1t, E_, P_, 256, 0 };
  ca.d[d++] = { ow2, ow2t, P_, P_, 256, 0 };

  // ---- prologue ----
  zero_kernel<<<1, 1, 0, stream>>>(entp);
  convert_x_kernel<<<1024, 256, 0, stream>>>(x, Xb, Xlo, T_ * E_ / 4);
  build_router_w_kernel<<<1536, 256, 0, stream>>>(rw1, rW1s);
  convert_wt_kernel<<<dim3(64, 20), 256, 0, stream>>>(ca);
  build_ball_kernel<<<8, 256, 0, stream>>>(gb3, lb2, Ball);

  // ---- router: split-bf16 GEMM (MODE 3, fp32 Hr) + standalone logits ----
  gemm_bf16_k<3, true, true><<<dim3(T_ / 128, 4), 256, 0, stream>>>(
      Xb, rW1s, rb1, Hr, nullptr, T_, 512, 768, 0, Xlo, 256, 768, 512, nullptr);
  logits_kernel<<<T_ / 256, 256, 0, stream>>>(Hr, rw2, rb2, wtok, entp);

  // ---- global experts: L1 -> gh1h (T/2 chunks, aliases Xlo), L2 scaled -> bufP ----
  for (int s = 0; s < 2; ++s) {
    for (int half = 0; half < 2; ++half) {
      const size_t r0 = (size_t)half * (T_ / 2);
      gemm_bf16_k<0, true, false><<<dim3(T_ / 256, 4), 256, 0, stream>>>(
          Xb + r0 * 256, gW1t + (size_t)s * 512 * 256, gb1 + s * 512, gh1h, nullptr,
          T_ / 2, 512, 256, 0, nullptr, 256, 256, 512, nullptr);
      gemm_bf16_k<4, true, false><<<dim3(T_ / 256, 4), 256, 0, stream>>>(
          gh1h, gW2t + (size_t)s * 512 * 512, gb2 + s * 512, bufP + r0 * 1024 + s * 512,
          wtok + r0 * 8, T_ / 2, 512, 512, s, nullptr, 512, 512, 1024, nullptr);
    }
  }
  // global final: pred = bufP @ BfG + sum_e wtok[:,e]*Ball[e]
  gemm_bf16_k<6, true, false><<<dim3(T_ / 128, 2), 256, 0, stream>>>(
      bufP, BfG, nullptr, pred, wtok, T_, 256, 1024, 0, nullptr, 1024, 1024, 256, Ball);

  // ---- local experts: pair L1 (scaled, N=1024) -> bufP; pair final -> pred += ----
  for (int p = 0; p < 3; ++p) {
    gemm_bf16_k<4, true, false><<<dim3(T_ / 128, 8), 256, 0, stream>>>(
        Xb, lW1tP + (size_t)p * 1024 * 256, lb1 + p * 1024, bufP, wtok,
        T_, 1024, 256, 2 + 2 * p, nullptr, 256, 256, 1024, nullptr);
    gemm_bf16_k<6, false, false><<<dim3(T_ / 128, 2), 256, 0, stream>>>(
        bufP, BfL + (size_t)p * 256 * 1024, nullptr, pred, wtok,
        T_, 256, 1024, 0, nullptr, 1024, 1024, 256, nullptr);
  }

  // ---- tail ----
  mean_kernel<<<96, 256, 0, stream>>>(pred, meanz);
  te_kernel<<<96, 256, 0, stream>>>(meanz, tew, teb, reprs);
  wc_kernel<<<32, 128, 0, stream>>>(reprs, wmem, wcw, wcb, swp);
  weighted_kernel<<<TBC_, 256, 0, stream>>>(pred, swp, wghtB);

  gemm_bf16_k<0, true, false><<<dim3(TBC_ / 128, 2), 256, 0, stream>>>(
      wghtB, ow1t, ob1, out1B, nullptr, TBC_, 256, 256, 0, nullptr, 256, 256, 256, nullptr);
  gemm_bf16_k<2, true, false><<<dim3(TBC_ / 128, 2), 256, 0, stream>>>(
      out1B, ow2t, ob2, out, nullptr, TBC_, 256, 256, 0, nullptr, 256, 256, 256, nullptr);

  finalize_kernel<<<1, 1, 0, stream>>>(entp, out);
  (void)in_sizes; (void)n_in; (void)out_size; (void)ws_size;
}